// Round 8
// baseline (266.225 us; speedup 1.0000x reference)
//
#include <hip/hip_runtime.h>
#include <hip/hip_fp16.h>
#include <math.h>

#define B_ 128
#define C_ 10
#define R_ 8192
#define I_ 8
#define O_ 16

typedef __attribute__((ext_vector_type(8))) _Float16 half8;
typedef __attribute__((ext_vector_type(16))) float f32x16;

#define WROW 64            // uints per W row: 16 o * 4
#define WZERO 80           // zero-row index (block-diagonal A trick)
#define SBO (C_ * B_ * O_) // 20480

__device__ __forceinline__ unsigned pk2(float a, float b) {
    __half2 h = __floats2half2_rn(a, b);
    return *(unsigned*)&h;
}

// ---------------------------------------------------------------------------
// transpose_x: x[B][R][8] fp32 -> xth[R][B] uint4 (8 fp16). LDS-tiled,
// coalesced both sides. grid (R/32, B/32) = (256,4).
// ---------------------------------------------------------------------------
__global__ __launch_bounds__(256) void transpose_x(const float* __restrict__ x,
                                                   uint4* __restrict__ xth) {
    __shared__ uint4 tile[32][33];
    const int r0 = blockIdx.x * 32, b0 = blockIdx.y * 32;
#pragma unroll
    for (int k = 0; k < 4; ++k) {
        const int f = k * 256 + threadIdx.x;
        const int bl = f >> 5, rl = f & 31;
        const float4* src = (const float4*)(x + ((size_t)(b0 + bl) * R_ + r0 + rl) * 8);
        const float4 v0 = src[0], v1 = src[1];
        tile[bl][rl] = make_uint4(pk2(v0.x, v0.y), pk2(v0.z, v0.w),
                                  pk2(v1.x, v1.y), pk2(v1.z, v1.w));
    }
    __syncthreads();
#pragma unroll
    for (int k = 0; k < 4; ++k) {
        const int f = k * 256 + threadIdx.x;
        const int rl = f >> 5, bl = f & 31;
        xth[(size_t)(r0 + rl) * B_ + b0 + bl] = tile[bl][rl];
    }
}

// ---------------------------------------------------------------------------
// fused_iter: one routing iteration. grid 1024 (r-tiles of 8), block 256.
// W (all 10 c) staged once in LDS fp16 (20.3 KB). x fragments live in
// REGISTERS (4 x uint4 per lane, from xth) - no x LDS, no x staging barrier.
// Per (c, r-pair): ONE 32x32x16 f16 MFMA computes u[2r x 16o][32b].
// mode 0: cij = 0.1, MFMA-chained per c; mode 1: phase2 D, phase3 softmax.
// Output: part[slot=blockIdx.x][c][b][o] fp16 partial s sums.
// ---------------------------------------------------------------------------
__global__ __launch_bounds__(256, 4) void fused_iter(const uint4* __restrict__ xth,
                                                     const float* __restrict__ w,
                                                     const float* __restrict__ vsum,  // [C][B][16]
                                                     __half* __restrict__ part,
                                                     int mode) {
    __shared__ unsigned wls[(80 + 1) * WROW];   // 20.25 KB

    const int tid = threadIdx.x;
    const int wave = tid >> 6;
    const int lane = tid & 63;
    const int n = lane & 31;
    const int g = lane >> 5;            // k-half / o-half selector
    const int rp_m = (lane & 31) >> 4;  // r' of this lane's A row
    const int o_m = lane & 15;          // o of this lane's A row
    const int b = wave * 32 + n;        // global batch 0..127
    const int r0 = blockIdx.x * 8;

    // ---- stage W for ALL c fp16: wls[c*8+r][o][4 b32], once ----
#pragma unroll
    for (int k = 0; k < 5; ++k) {
        const int id = k * 256 + tid;           // 0..1279 = (c, r, o)
        const int o = id & 15;
        const int r = (id >> 4) & 7;
        const int c = id >> 7;
        const float* wp = w + ((size_t)(c * R_ + r0 + r) * 8) * 16 + o;
        const float f0 = wp[0],  f1 = wp[16],  f2 = wp[32],  f3 = wp[48];
        const float f4 = wp[64], f5 = wp[80],  f6 = wp[96],  f7 = wp[112];
        *(uint4*)(wls + (c * 8 + r) * WROW + o * 4) =
            make_uint4(pk2(f0, f1), pk2(f2, f3), pk2(f4, f5), pk2(f6, f7));
    }
    if (tid < WROW) wls[WZERO * WROW + tid] = 0u;

    // ---- x fragments in registers: lane b, B-rows r = 2rp+g ----
    half8 xf[4];
#pragma unroll
    for (int rp = 0; rp < 4; ++rp) {
        const uint4 t = xth[(size_t)(r0 + 2 * rp + g) * B_ + b];
        xf[rp] = *(const half8*)&t;
    }
    __syncthreads();

    f32x16 Z;
#pragma unroll
    for (int j = 0; j < 16; ++j) Z[j] = 0.f;

    const int act = (g == rp_m);

    float dacc[8];
#pragma unroll
    for (int j = 0; j < 8; ++j) dacc[j] = 0.f;

    // ================= PHASE 2: denominators (mode 1) =================
    if (mode) {
#pragma unroll 1
        for (int c = 0; c < C_; ++c) {
            const float4* vp = (const float4*)(vsum + ((size_t)c * B_ + b) * O_ + 4 * g);
            const float4 va = vp[0];   // o = 4g..4g+3
            const float4 vb = vp[2];   // o = 8+4g..
#pragma unroll
            for (int rp = 0; rp < 4; ++rp) {
                const int woff = act ? ((c * 8 + 2 * rp + g) * WROW + o_m * 4)
                                     : (WZERO * WROW);   // broadcast zero slot
                const half8 a = *(const half8*)(wls + woff);
                const f32x16 u = __builtin_amdgcn_mfma_f32_32x32x16_f16(a, xf[rp], Z, 0, 0, 0);
                float p0 = u[0] * va.x + u[1] * va.y + u[2] * va.z + u[3] * va.w
                         + u[4] * vb.x + u[5] * vb.y + u[6] * vb.z + u[7] * vb.w;
                float p1 = u[8] * va.x + u[9] * va.y + u[10] * va.z + u[11] * va.w
                         + u[12] * vb.x + u[13] * vb.y + u[14] * vb.z + u[15] * vb.w;
                p0 += __shfl_xor(p0, 32);
                p1 += __shfl_xor(p1, 32);
                dacc[2 * rp]     += __expf(p0);
                dacc[2 * rp + 1] += __expf(p1);
            }
        }
#pragma unroll
        for (int j = 0; j < 8; ++j) dacc[j] = 1.0f / dacc[j];
    }

    // ================= PHASE 3: s accumulation =================
    if (mode) {
#pragma unroll 1
        for (int c = 0; c < C_; ++c) {
            const float4* vp = (const float4*)(vsum + ((size_t)c * B_ + b) * O_ + 4 * g);
            const float4 va = vp[0], vb = vp[2];
            f32x16 acc;
#pragma unroll
            for (int j = 0; j < 16; ++j) acc[j] = 0.f;
#pragma unroll
            for (int rp = 0; rp < 4; ++rp) {
                const int woff = act ? ((c * 8 + 2 * rp + g) * WROW + o_m * 4)
                                     : (WZERO * WROW);
                const half8 a = *(const half8*)(wls + woff);
                const f32x16 u = __builtin_amdgcn_mfma_f32_32x32x16_f16(a, xf[rp], Z, 0, 0, 0);
                float p0 = u[0] * va.x + u[1] * va.y + u[2] * va.z + u[3] * va.w
                         + u[4] * vb.x + u[5] * vb.y + u[6] * vb.z + u[7] * vb.w;
                float p1 = u[8] * va.x + u[9] * va.y + u[10] * va.z + u[11] * va.w
                         + u[12] * vb.x + u[13] * vb.y + u[14] * vb.z + u[15] * vb.w;
                p0 += __shfl_xor(p0, 32);
                p1 += __shfl_xor(p1, 32);
                const float c0 = __expf(p0) * dacc[2 * rp];
                const float c1 = __expf(p1) * dacc[2 * rp + 1];
#pragma unroll
                for (int j = 0; j < 8; ++j)  acc[j] += c0 * u[j];
#pragma unroll
                for (int j = 8; j < 16; ++j) acc[j] += c1 * u[j];
            }
            const float f0 = acc[0] + acc[8],  f1 = acc[1] + acc[9];
            const float f2 = acc[2] + acc[10], f3 = acc[3] + acc[11];
            const float f4 = acc[4] + acc[12], f5 = acc[5] + acc[13];
            const float f6 = acc[6] + acc[14], f7 = acc[7] + acc[15];
            __half* pp = part + (((size_t)blockIdx.x * C_ + c) * B_ + b) * O_;
            *(uint2*)(pp + 4 * g)     = make_uint2(pk2(f0, f1), pk2(f2, f3));
            *(uint2*)(pp + 8 + 4 * g) = make_uint2(pk2(f4, f5), pk2(f6, f7));
        }
    } else {
        // mode 0: cij uniform 0.1 -> chain the 4 MFMAs into one accumulator
#pragma unroll 1
        for (int c = 0; c < C_; ++c) {
            f32x16 u = Z;
#pragma unroll
            for (int rp = 0; rp < 4; ++rp) {
                const int woff = act ? ((c * 8 + 2 * rp + g) * WROW + o_m * 4)
                                     : (WZERO * WROW);
                const half8 a = *(const half8*)(wls + woff);
                u = __builtin_amdgcn_mfma_f32_32x32x16_f16(a, xf[rp], u, 0, 0, 0);
            }
            const float f0 = 0.1f * (u[0] + u[8]),  f1 = 0.1f * (u[1] + u[9]);
            const float f2 = 0.1f * (u[2] + u[10]), f3 = 0.1f * (u[3] + u[11]);
            const float f4 = 0.1f * (u[4] + u[12]), f5 = 0.1f * (u[5] + u[13]);
            const float f6 = 0.1f * (u[6] + u[14]), f7 = 0.1f * (u[7] + u[15]);
            __half* pp = part + (((size_t)blockIdx.x * C_ + c) * B_ + b) * O_;
            *(uint2*)(pp + 4 * g)     = make_uint2(pk2(f0, f1), pk2(f2, f3));
            *(uint2*)(pp + 8 + 4 * g) = make_uint2(pk2(f4, f5), pk2(f6, f7));
        }
    }
}

// ---------------------------------------------------------------------------
// reduce1: part2[by][t] = sum of 64 slot-partials. grid (80,16) = 1280 blocks.
// ---------------------------------------------------------------------------
__global__ __launch_bounds__(256) void reduce1(const __half* __restrict__ part,
                                               float* __restrict__ part2) {
    const int t = blockIdx.x * 256 + threadIdx.x;
    const int s0 = blockIdx.y * 64;
    const __half* p = part + (size_t)s0 * SBO + t;
    float sum = 0.f;
#pragma unroll 8
    for (int s = 0; s < 64; ++s)
        sum += __half2float(p[(size_t)s * SBO]);
    part2[(size_t)blockIdx.y * SBO + t] = sum;
}

// ---------------------------------------------------------------------------
// finish_pass: sum 16 fp32 partials + squash. grid 80.
// t = (c*128+b)*16+o; o spans 16 consecutive lanes -> shfl reduce for ||s||^2.
// mode 0: vsum = v; 1: vsum += v; 2: out = v.
// ---------------------------------------------------------------------------
__global__ __launch_bounds__(256) void finish_pass(const float* __restrict__ part2,
                                                   float* __restrict__ vsum,   // [C][B][16]
                                                   float* __restrict__ out,    // [B][C][16]
                                                   int mode) {
    const int t = blockIdx.x * 256 + threadIdx.x;
    float sum = 0.f;
#pragma unroll
    for (int s = 0; s < 16; ++s)
        sum += part2[(size_t)s * SBO + t];

    float sq = sum * sum;
    sq += __shfl_xor(sq, 1);
    sq += __shfl_xor(sq, 2);
    sq += __shfl_xor(sq, 4);
    sq += __shfl_xor(sq, 8);
    const float scale = sq / ((1.0f + sq) * sqrtf(sq + 1e-8f));
    const float v = scale * sum;

    if (mode == 0) {
        vsum[t] = v;
    } else if (mode == 1) {
        vsum[t] += v;
    } else {
        const int o = t & 15, b = (t >> 4) & 127, c = t >> 11;
        out[((size_t)b * C_ + c) * O_ + o] = v;
    }
}

extern "C" void kernel_launch(void* const* d_in, const int* in_sizes, int n_in,
                              void* d_out, int out_size, void* d_ws, size_t ws_size,
                              hipStream_t stream) {
    const float* x = (const float*)d_in[0];   // [B,R,8]
    const float* w = (const float*)d_in[1];   // [C,R,8,16]
    float* out = (float*)d_out;               // [B,C,16]

    uint4* xth   = (uint4*)d_ws;                          // R*B uint4 = 16.78 MB
    __half* part = (__half*)(xth + (size_t)R_ * B_);      // 1024*20480 fp16 = 41.9 MB
    float* part2 = (float*)(part + (size_t)1024 * SBO);   // 16*20480 fp32 = 1.3 MB
    float* vsum  = part2 + (size_t)16 * SBO;              // 20480 f ([C][B][16])

    const dim3 tgrid(R_ / 32, B_ / 32);   // (256,4)
    const dim3 fgrid(R_ / 8);             // 1024
    const dim3 rgrid(80, 16);             // 1280 blocks
    const dim3 ggrid(80);

    transpose_x<<<tgrid, 256, 0, stream>>>(x, xth);

    // iteration 0 (uniform cij; vsum not read)
    fused_iter<<<fgrid, 256, 0, stream>>>(xth, w, vsum, part, 0);
    reduce1<<<rgrid, 256, 0, stream>>>(part, part2);
    finish_pass<<<ggrid, 256, 0, stream>>>(part2, vsum, out, 0);

    // iteration 1
    fused_iter<<<fgrid, 256, 0, stream>>>(xth, w, vsum, part, 1);
    reduce1<<<rgrid, 256, 0, stream>>>(part, part2);
    finish_pass<<<ggrid, 256, 0, stream>>>(part2, vsum, out, 1);

    // iteration 2 (final: write out)
    fused_iter<<<fgrid, 256, 0, stream>>>(xth, w, vsum, part, 1);
    reduce1<<<rgrid, 256, 0, stream>>>(part, part2);
    finish_pass<<<ggrid, 256, 0, stream>>>(part2, vsum, out, 2);
}